// Round 1
// 278.353 us; speedup vs baseline: 1.0692x; 1.0692x over previous
//
#include <hip/hip_runtime.h>
#include <hip/hip_bf16.h>
#include <stdint.h>

// Problem constants (B,T,C) = (4,4096,1024)
#define TT 4096
#define BB 4
#define CC 1024
#define MM (BB * TT)          // 16384 rows
#define NCHUNK 64             // scan chunks along T
#define CHUNK_T (TT / NCHUNK) // 64 steps per chunk
#define NCHAIN (BB * CC)      // 4096 independent scan chains

typedef float f32x4 __attribute__((ext_vector_type(4)));
typedef __bf16 bf16x8 __attribute__((ext_vector_type(8)));

__device__ __forceinline__ float b2f(ushort u) {
  union { float f; uint32_t v; } x; x.v = ((uint32_t)u) << 16; return x.f;
}
__device__ __forceinline__ ushort f2b(float f) { // RNE fp32->bf16
  union { float f; uint32_t u; } x; x.f = f;
  uint32_t r = x.u + 0x7fffu + ((x.u >> 16) & 1u);
  return (ushort)(r >> 16);
}

// async global->LDS, 16B per lane. LDS dest must be uniform-base + lane*16.
__device__ __forceinline__ void async_copy16(const ushort* g, ushort* l) {
  __builtin_amdgcn_global_load_lds(
      (__attribute__((address_space(1))) void*)(g),
      (__attribute__((address_space(3))) void*)(l), 16, 0, 0);
}

// One kernel converts x, Wf, Wg, Wp to bf16. Sizes in float4 units:
// x: 4194304, each W: 262144. Total 4980736 = 19456 * 256 exactly.
__global__ __launch_bounds__(256) void cvt_all(const float* __restrict__ x,
                                               const float* __restrict__ wf,
                                               const float* __restrict__ wg,
                                               const float* __restrict__ wp,
                                               ushort* __restrict__ xb,
                                               ushort* __restrict__ wcat,
                                               ushort* __restrict__ wpb) {
  const int i = blockIdx.x * 256 + threadIdx.x;
  const float* s; ushort* d; int off;
  if (i < 4194304)            { s = x;  d = xb;              off = i; }
  else if (i < 4456448)       { s = wf; d = wcat;            off = i - 4194304; }
  else if (i < 4718592)       { s = wg; d = wcat + 1048576;  off = i - 4456448; }
  else                        { s = wp; d = wpb;             off = i - 4718592; }
  float4 v = ((const float4*)s)[off];
  ushort4 o;
  o.x = f2b(v.x); o.y = f2b(v.y); o.z = f2b(v.z); o.w = f2b(v.w);
  ((ushort4*)d)[off] = o;
}

// ===========================================================================
// ROUND-7: 256x256 tile, BK=32, 8 waves (2Mx4N), 4-deep LDS ring (128 KiB),
// counted vmcnt(4) -- loads stay in flight ACROSS barriers (T3/T4 regime).
//
// Pipeline invariant entering K-tile t:   ring slot t&3 landed + barrier'd,
// tile t+1's 4 loads/thread in flight.   Body: 12x ds_read_b128 (tile t),
// issue 4 loads for tile t+2 into slot (t+2)&3 (last read at tile t-2, two
// raw s_barriers ago -> WAR safe), 32 MFMA under setprio(1), then
// s_waitcnt vmcnt(4) (== "tile t+1 landed, t+2 may fly") + raw s_barrier +
// sched_barrier(0).  Main loop NEVER drains vmcnt to 0.
//
// LDS rows are 64 B (32 bf16). Swizzle: 16-B octet o of row r stored at slot
// o ^ ((r>>1)&3); staging pre-swizzles the GLOBAL source octet so LDS dests
// stay lane-linear (async-copy compatible, rule #21 involution). Fragment
// reads: slot = kq ^ ((rlo>>1)&3) -> 2 lanes per 4-bank group per quarter-
// wave (conflict-free class, same structure as the 0-conflict round-6 read).
//
// Operand-swapped MFMA (proven R3): n on reg axis -> packed 4-wide stores.
// MODE 0: f32x4 stores. MODE 1: sigmoid (n0<1024) / tanh, ushort4 stores.
// ===========================================================================
template <int MODE>
__global__ __launch_bounds__(512, 2) void gemm_bt(const ushort* __restrict__ A,
                                                  const ushort* __restrict__ Bw,
                                                  float* __restrict__ outF,
                                                  ushort* __restrict__ outB, int N) {
  constexpr int K = CC; // 1024 -> 32 K-tiles of 32
  __shared__ __align__(16) ushort sA[4 * 256 * 32]; // 64 KB ring (4 slots)
  __shared__ __align__(16) ushort sB[4 * 256 * 32]; // 64 KB ring

  const int tid = threadIdx.x;
  const int lane = tid & 63;
  const int w = tid >> 6;  // 0..7
  const int wm = w >> 2;   // 0..1: 128-row M half
  const int wn = w & 3;    // 0..3: 64-col N quarter

  // XCD-aware bijective swizzle (nwg = 512 or 256, both % 8 == 0)
  const int nbx = N >> 8;
  const int cpx = (int)gridDim.x >> 3;
  const int bid = blockIdx.x;
  const int wg = (bid & 7) * cpx + (bid >> 3);
  const long n0 = (long)(wg % nbx) << 8;
  const long m0 = (long)(wg / nbx) << 8;

  // ---- staging addressing: wave w stages A rows w*16 & (w+8)*16, same for B.
  // chunk = 16 rows x 64 B; lane -> row = lane>>2, LDS octet = lane&3,
  // global octet pre-swizzled: (lane&3) ^ ((row>>1)&3) = (lane&3)^((lane>>3)&3)
  const int srow = lane >> 2;
  const int goct = (lane & 3) ^ ((lane >> 3) & 3);
  const ushort* gA0 = A + (m0 + w * 16 + srow) * K + goct * 8;
  const ushort* gB0 = Bw + (n0 + w * 16 + srow) * K + goct * 8;
  const ushort* gA1 = gA0 + 128 * (long)K;
  const ushort* gB1 = gB0 + 128 * (long)K;
  ushort* dA0 = &sA[w * 512 + lane * 8];
  ushort* dA1 = dA0 + 4096; // rows +128
  ushort* dB0 = &sB[w * 512 + lane * 8];
  ushort* dB1 = dB0 + 4096;

  // ---- fragment read addressing (per-lane, constant across tiles/frags)
  const int rlo = lane & 15;
  const int kq = lane >> 4;
  const int slot = kq ^ ((rlo >> 1) & 3);
  const ushort* rA = &sA[wm * 4096 + rlo * 32 + slot * 8]; // + buf*8192 + i*512
  const ushort* rB = &sB[wn * 2048 + rlo * 32 + slot * 8]; // + buf*8192 + j*512

  f32x4 acc[8][4];
#pragma unroll
  for (int i = 0; i < 8; ++i)
#pragma unroll
    for (int j = 0; j < 4; ++j) acc[i][j] = (f32x4){0.f, 0.f, 0.f, 0.f};

  auto stage = [&](int buf, int ts) {
    const int o = ts * 32;        // k offset in elements
    const int lo = buf * 8192;    // ring-slot offset in elements
    async_copy16(gA0 + o, dA0 + lo);
    async_copy16(gA1 + o, dA1 + lo);
    async_copy16(gB0 + o, dB0 + lo);
    async_copy16(gB1 + o, dB1 + lo);
  };

  auto body = [&](int buf, bool do_stage, int ts) {
    bf16x8 af[8], bfr[4];
    const int lo = buf * 8192;
#pragma unroll
    for (int i = 0; i < 8; ++i) af[i] = *(const bf16x8*)(rA + lo + i * 512);
#pragma unroll
    for (int j = 0; j < 4; ++j) bfr[j] = *(const bf16x8*)(rB + lo + j * 512);
    if (do_stage) stage((buf + 2) & 3, ts);
    __builtin_amdgcn_s_setprio(1);
#pragma unroll
    for (int i = 0; i < 8; ++i)
#pragma unroll
      for (int j = 0; j < 4; ++j)
        acc[i][j] = __builtin_amdgcn_mfma_f32_16x16x32_bf16(bfr[j], af[i], acc[i][j], 0, 0, 0);
    __builtin_amdgcn_s_setprio(0);
  };

  // prologue: tiles 0,1 staged; wait tile 0 (vmcnt(4): 4 newest = tile 1)
  stage(0, 0);
  stage(1, 1);
  asm volatile("s_waitcnt vmcnt(4)" ::: "memory");
  __builtin_amdgcn_s_barrier();
  __builtin_amdgcn_sched_barrier(0);

  // main loop: t = 0..27 (buf = t&3 == u), steady-state vmcnt(4)
  for (int t4 = 0; t4 < 7; ++t4) {
#pragma unroll
    for (int u = 0; u < 4; ++u) {
      body(u, true, t4 * 4 + u + 2);
      asm volatile("s_waitcnt vmcnt(4)" ::: "memory");
      __builtin_amdgcn_s_barrier();
      __builtin_amdgcn_sched_barrier(0);
    }
  }
  // tail: t = 28..31
  body(0, true, 30);
  asm volatile("s_waitcnt vmcnt(4)" ::: "memory");
  __builtin_amdgcn_s_barrier();
  __builtin_amdgcn_sched_barrier(0);
  body(1, true, 31);
  asm volatile("s_waitcnt vmcnt(4)" ::: "memory");
  __builtin_amdgcn_s_barrier();
  __builtin_amdgcn_sched_barrier(0);
  body(2, false, 0);
  asm volatile("s_waitcnt vmcnt(0)" ::: "memory"); // drain only at tail
  __builtin_amdgcn_s_barrier();
  __builtin_amdgcn_sched_barrier(0);
  body(3, false, 0);

  // Swapped C/D mapping (R3-verified): m = lane&15 axis, n = (lane>>4)*4 + reg.
  const int mloc = lane & 15;
  const int nq = (lane >> 4) * 4;
#pragma unroll
  for (int i = 0; i < 8; ++i) {
    const long m = m0 + wm * 128 + i * 16 + mloc;
#pragma unroll
    for (int j = 0; j < 4; ++j) {
      const long nb = n0 + wn * 64 + j * 16 + nq; // 4 consecutive n
      const f32x4 v = acc[i][j];
      if (MODE == 0) {
        *(f32x4*)(outF + m * N + nb) = v;
      } else {
        float act[4];
        if (n0 < CC) { // sigmoid region (block-uniform; 256 | 1024)
#pragma unroll
          for (int r = 0; r < 4; ++r)
            act[r] = __builtin_amdgcn_rcpf(1.f + __expf(-v[r]));
        } else {       // tanh = 1 - 2/(exp(2v)+1)
#pragma unroll
          for (int r = 0; r < 4; ++r)
            act[r] = fmaf(-2.f, __builtin_amdgcn_rcpf(1.f + __expf(2.f * v[r])), 1.f);
        }
        ushort4 o;
        o.x = f2b(act[0]); o.y = f2b(act[1]); o.z = f2b(act[2]); o.w = f2b(act[3]);
        *(ushort4*)(outB + m * (long)N + nb) = o;
      }
    }
  }
}

// ===== Scan: R1-style 3-pass (cheapest measured), vectorized 4 chains/thread =====
// P layout: [m=b*T+t][0..1023]=f (bf16), [1024..2047]=g (bf16)
__global__ __launch_bounds__(256) void scan_pass1(const ushort* __restrict__ P,
                                                  float* __restrict__ cA,
                                                  float* __restrict__ cB) {
  const int pc = blockIdx.x * 256 + threadIdx.x; // chain quad 0..1023
  const int chunk = blockIdx.y;
  const int b = pc >> 8, c4 = (pc & 255) * 4;
  const ushort4* p =
      (const ushort4*)(P + (size_t)(b * TT + chunk * CHUNK_T) * (2 * CC) + c4);
  float A[4] = {1.f, 1.f, 1.f, 1.f};
  float h[4] = {0.f, 0.f, 0.f, 0.f};
#pragma unroll 4
  for (int i = 0; i < CHUNK_T; ++i) {
    const ushort4 fu = p[0];
    const ushort4 gu = p[CC / 4];
    p += 2 * CC / 4;
    const float f[4] = {b2f(fu.x), b2f(fu.y), b2f(fu.z), b2f(fu.w)};
    const float g[4] = {b2f(gu.x), b2f(gu.y), b2f(gu.z), b2f(gu.w)};
#pragma unroll
    for (int r = 0; r < 4; ++r) {
      A[r] *= f[r];
      h[r] = fmaf(f[r], h[r], (1.f - f[r]) * g[r]);
    }
  }
  const int ci = chunk * NCHAIN + b * CC + c4;
  *(f32x4*)(cA + ci) = (f32x4){A[0], A[1], A[2], A[3]};
  *(f32x4*)(cB + ci) = (f32x4){h[0], h[1], h[2], h[3]};
}

__global__ __launch_bounds__(256) void scan_pass2(const float* __restrict__ cA,
                                                  const float* __restrict__ cB,
                                                  float* __restrict__ hinit) {
  const int chain = blockIdx.x * 256 + threadIdx.x; // 0..4095
  float h = 0.f;
  for (int j = 0; j < NCHUNK; ++j) {
    hinit[j * NCHAIN + chain] = h; // exclusive carry
    h = fmaf(cA[j * NCHAIN + chain], h, cB[j * NCHAIN + chain]);
  }
}

__global__ __launch_bounds__(256) void scan_pass3(const ushort* __restrict__ P,
                                                  const float* __restrict__ hinit,
                                                  ushort* __restrict__ H) {
  const int pc = blockIdx.x * 256 + threadIdx.x;
  const int chunk = blockIdx.y;
  const int b = pc >> 8, c4 = (pc & 255) * 4;
  f32x4 hv = *(const f32x4*)(hinit + chunk * NCHAIN + b * CC + c4);
  float h[4] = {hv[0], hv[1], hv[2], hv[3]};
  const ushort4* p =
      (const ushort4*)(P + (size_t)(b * TT + chunk * CHUNK_T) * (2 * CC) + c4);
  ushort4* hp = (ushort4*)(H + (size_t)(b * TT + chunk * CHUNK_T) * CC + c4);
#pragma unroll 4
  for (int i = 0; i < CHUNK_T; ++i) {
    const ushort4 fu = p[0];
    const ushort4 gu = p[CC / 4];
    p += 2 * CC / 4;
    const float f[4] = {b2f(fu.x), b2f(fu.y), b2f(fu.z), b2f(fu.w)};
    const float g[4] = {b2f(gu.x), b2f(gu.y), b2f(gu.z), b2f(gu.w)};
    ushort4 o;
#pragma unroll
    for (int r = 0; r < 4; ++r)
      h[r] = fmaf(f[r], h[r], (1.f - f[r]) * g[r]);
    o.x = f2b(h[0]); o.y = f2b(h[1]); o.z = f2b(h[2]); o.w = f2b(h[3]);
    *hp = o;
    hp += CC / 4;
  }
}

extern "C" void kernel_launch(void* const* d_in, const int* in_sizes, int n_in,
                              void* d_out, int out_size, void* d_ws, size_t ws_size,
                              hipStream_t stream) {
  const float* x  = (const float*)d_in[0];
  const float* Wf = (const float*)d_in[1];
  const float* Wg = (const float*)d_in[2];
  const float* Wp = (const float*)d_in[3];

  // workspace layout (bytes); H aliases xb (xb dead after gates GEMM, stream-ordered)
  char* ws = (char*)d_ws;
  ushort* xb   = (ushort*)(ws);                                  // 33554432 B
  ushort* Hb   = xb;                                             // alias
  ushort* Wcat = (ushort*)(ws + 33554432);                       //  4194304 B (Wf||Wg)
  ushort* Wpb  = (ushort*)(ws + 33554432 + 4194304);             //  2097152 B
  ushort* P    = (ushort*)(ws + 33554432 + 4194304 + 2097152);   // 67108864 B (f||g bf16)
  char* tail   = ws + 33554432 + 4194304 + 2097152 + 67108864;
  float* cA    = (float*)(tail);                                 // 1 MiB (64*4096*4)
  float* cB    = (float*)(tail + 1048576);                       // 1 MiB
  float* hinit = (float*)(tail + 2097152);                       // 1 MiB
  (void)ws_size; (void)in_sizes; (void)n_in; (void)out_size;

  // 1) all fp32 -> bf16 conversions in one launch
  cvt_all<<<19456, 256, 0, stream>>>(x, Wf, Wg, Wp, xb, Wcat, Wpb);

  // 2) gates GEMM: [16384 x 2048] = xb @ Wcat^T, fused sigmoid/tanh -> P (bf16)
  // 256x256 tiles: (2048/256) x (16384/256) = 512 blocks, 512 threads
  gemm_bt<1><<<512, 512, 0, stream>>>(xb, Wcat, nullptr, P, 2 * CC);

  // 3) chunked scan: 3-pass (per-chunk compose, carry scan, fixup)
  dim3 gs(NCHAIN / 4 / 256, NCHUNK);
  scan_pass1<<<gs, 256, 0, stream>>>(P, cA, cB);
  scan_pass2<<<NCHAIN / 256, 256, 0, stream>>>(cA, cB, hinit);
  scan_pass3<<<gs, 256, 0, stream>>>(P, hinit, Hb);

  // 4) projection GEMM: out = H @ Wp^T (fp32), 256x256 tiles -> 256 blocks
  gemm_bt<0><<<256, 512, 0, stream>>>(Hb, Wpb, (float*)d_out, nullptr, CC);
}

// Round 2
// 268.341 us; speedup vs baseline: 1.1091x; 1.0373x over previous
//
#include <hip/hip_runtime.h>
#include <hip/hip_bf16.h>
#include <stdint.h>

// Problem constants (B,T,C) = (4,4096,1024)
#define TT 4096
#define BB 4
#define CC 1024
#define MM (BB * TT)          // 16384 rows
#define NCHUNK 128            // scan chunks along T (R8: 64 -> 128, 2x blocks)
#define CHUNK_T (TT / NCHUNK) // 32 steps per chunk
#define NCHAIN (BB * CC)      // 4096 independent scan chains

typedef float f32x4 __attribute__((ext_vector_type(4)));
typedef __bf16 bf16x8 __attribute__((ext_vector_type(8)));

__device__ __forceinline__ float b2f(ushort u) {
  union { float f; uint32_t v; } x; x.v = ((uint32_t)u) << 16; return x.f;
}
__device__ __forceinline__ ushort f2b(float f) { // RNE fp32->bf16
  union { float f; uint32_t u; } x; x.f = f;
  uint32_t r = x.u + 0x7fffu + ((x.u >> 16) & 1u);
  return (ushort)(r >> 16);
}

// async global->LDS, 16B per lane. LDS dest must be uniform-base + lane*16.
__device__ __forceinline__ void async_copy16(const ushort* g, ushort* l) {
  __builtin_amdgcn_global_load_lds(
      (__attribute__((address_space(1))) void*)(g),
      (__attribute__((address_space(3))) void*)(l), 16, 0, 0);
}

// One kernel converts x, Wf, Wg, Wp to bf16. Sizes in float4 units:
// x: 4194304, each W: 262144. Total 4980736 = 19456 * 256 exactly.
__global__ __launch_bounds__(256) void cvt_all(const float* __restrict__ x,
                                               const float* __restrict__ wf,
                                               const float* __restrict__ wg,
                                               const float* __restrict__ wp,
                                               ushort* __restrict__ xb,
                                               ushort* __restrict__ wcat,
                                               ushort* __restrict__ wpb) {
  const int i = blockIdx.x * 256 + threadIdx.x;
  const float* s; ushort* d; int off;
  if (i < 4194304)            { s = x;  d = xb;              off = i; }
  else if (i < 4456448)       { s = wf; d = wcat;            off = i - 4194304; }
  else if (i < 4718592)       { s = wg; d = wcat + 1048576;  off = i - 4456448; }
  else                        { s = wp; d = wpb;             off = i - 4718592; }
  float4 v = ((const float4*)s)[off];
  ushort4 o;
  o.x = f2b(v.x); o.y = f2b(v.y); o.z = f2b(v.z); o.w = f2b(v.w);
  ((ushort4*)d)[off] = o;
}

// ===========================================================================
// ROUND-8: register-double-buffered 2-phase pipeline on the R7 ring.
//
// R7 measured 33% MfmaUtil at ~3210 cyc/K-tile vs 1184 cyc MFMA: the LDS
// read burst (96 KB/CU/tile) was serialized against the MFMA burst because
// each tile's MFMAs consumed reads issued in the same phase (lgkmcnt drain).
//
// R8 structure per K-tile t (BK=32, slot s = t&3 of the 4-deep ring):
//   ph0: issue ds_reads af[4..7](t) -> afY  (slot t)
//        issue stage of K-tile t+2  -> slot (t+2)&3
//        MFMA i-half0: afX x bfrCur          (no lgkm wait needed: afX/bfr
//                                             were read one phase earlier)
//   MID: s_waitcnt vmcnt(4)  (confirms slot t+1; slot t+2's 4 loads fly)
//        s_barrier + sched_barrier(0)
//   ph1: issue ds_reads af[0..3](t+1) -> afX, bfr(t+1) -> bfrNxt (slot t+1,
//        legal only now: it was confirmed at MID)
//        MFMA i-half1: afY x bfrCur
// Compiler auto-emits counted lgkmcnt (waits previous phase's reads, leaves
// the just-issued ones in flight) -> LDS drain overlaps the MFMA cluster.
// Hazard audit: slot sigma's last ds_read is lgkm-consumed by MFMA before
// the MID barrier of tile sigma+1; its overwrite (stage at tile sigma+2.ph0)
// is issued after that barrier -> WAR safe. Reads of slot t+1 are issued
// only after every wave's own slot-(t+1) gloads were vmcnt-confirmed and
// barrier-published. One barrier + one counted vmcnt per K-tile; vmcnt
// reaches 0 only at the tail.
//
// LDS swizzle unchanged from R7 (measured 0 conflicts): octet o of row r at
// slot o ^ ((r>>1)&3); staging pre-swizzles the GLOBAL octet (involution).
// Operand-swapped MFMA (R3): n on reg axis -> packed 4-wide stores.
// ===========================================================================

#define RD_A(dst, slotoff, ih)                                          \
  _Pragma("unroll") for (int i_ = 0; i_ < 4; ++i_)                      \
      dst[i_] = *(const bf16x8*)(rA + (slotoff) + ((ih)*4 + i_) * 512);

#define RD_B(dst, slotoff)                                              \
  _Pragma("unroll") for (int j_ = 0; j_ < 4; ++j_)                      \
      dst[j_] = *(const bf16x8*)(rB + (slotoff) + j_ * 512);

#define MM_HALF(afb, bfb, ih)                                           \
  __builtin_amdgcn_s_setprio(1);                                        \
  _Pragma("unroll") for (int i_ = 0; i_ < 4; ++i_)                      \
  _Pragma("unroll") for (int j_ = 0; j_ < 4; ++j_)                      \
      acc[(ih)*4 + i_][j_] = __builtin_amdgcn_mfma_f32_16x16x32_bf16(   \
          bfb[j_], afb[i_], acc[(ih)*4 + i_][j_], 0, 0, 0);             \
  __builtin_amdgcn_s_setprio(0);

#define CKPT(n)                                                         \
  asm volatile("s_waitcnt vmcnt(" #n ")" ::: "memory");                 \
  __builtin_amdgcn_s_barrier();                                         \
  __builtin_amdgcn_sched_barrier(0);

#define TILE_BODY(s, ns, ss, ts, bfrC, bfrN, DO_STAGE, CKN)             \
  RD_A(afY, (s) * 8192, 1);                                             \
  if (DO_STAGE) stage((ss), (ts));                                      \
  MM_HALF(afX, bfrC, 0);                                                \
  CKPT(CKN);                                                            \
  RD_A(afX, (ns) * 8192, 0);                                            \
  RD_B(bfrN, (ns) * 8192);                                              \
  MM_HALF(afY, bfrC, 1);

template <int MODE>
__global__ __launch_bounds__(512, 2) void gemm_bt(const ushort* __restrict__ A,
                                                  const ushort* __restrict__ Bw,
                                                  float* __restrict__ outF,
                                                  ushort* __restrict__ outB, int N) {
  constexpr int K = CC; // 1024 -> 32 K-tiles of 32
  __shared__ __align__(16) ushort sA[4 * 256 * 32]; // 64 KB ring (4 slots)
  __shared__ __align__(16) ushort sB[4 * 256 * 32]; // 64 KB ring

  const int tid = threadIdx.x;
  const int lane = tid & 63;
  const int w = tid >> 6;  // 0..7
  const int wm = w >> 2;   // 0..1: 128-row M half
  const int wn = w & 3;    // 0..3: 64-col N quarter

  // XCD-aware bijective swizzle (nwg = 512 or 256, both % 8 == 0)
  const int nbx = N >> 8;
  const int cpx = (int)gridDim.x >> 3;
  const int bid = blockIdx.x;
  const int wg = (bid & 7) * cpx + (bid >> 3);
  const long n0 = (long)(wg % nbx) << 8;
  const long m0 = (long)(wg / nbx) << 8;

  // ---- staging addressing: wave w stages A rows w*16 & (w+8)*16, same for B.
  // chunk = 16 rows x 64 B; lane -> row = lane>>2, LDS octet = lane&3,
  // global octet pre-swizzled: (lane&3) ^ ((row>>1)&3) = (lane&3)^((lane>>3)&3)
  const int srow = lane >> 2;
  const int goct = (lane & 3) ^ ((lane >> 3) & 3);
  const ushort* gA0 = A + (m0 + w * 16 + srow) * K + goct * 8;
  const ushort* gB0 = Bw + (n0 + w * 16 + srow) * K + goct * 8;
  const ushort* gA1 = gA0 + 128 * (long)K;
  const ushort* gB1 = gB0 + 128 * (long)K;
  ushort* dA0 = &sA[w * 512 + lane * 8];
  ushort* dA1 = dA0 + 4096; // rows +128
  ushort* dB0 = &sB[w * 512 + lane * 8];
  ushort* dB1 = dB0 + 4096;

  // ---- fragment read addressing (per-lane, constant across tiles/frags)
  const int rlo = lane & 15;
  const int kq = lane >> 4;
  const int slot = kq ^ ((rlo >> 1) & 3);
  const ushort* rA = &sA[wm * 4096 + rlo * 32 + slot * 8]; // + buf*8192 + i*512
  const ushort* rB = &sB[wn * 2048 + rlo * 32 + slot * 8]; // + buf*8192 + j*512

  f32x4 acc[8][4];
#pragma unroll
  for (int i = 0; i < 8; ++i)
#pragma unroll
    for (int j = 0; j < 4; ++j) acc[i][j] = (f32x4){0.f, 0.f, 0.f, 0.f};

  auto stage = [&](int buf, int ts) {
    const int o = ts * 32;        // k offset in elements
    const int lo = buf * 8192;    // ring-slot offset in elements
    async_copy16(gA0 + o, dA0 + lo);
    async_copy16(gA1 + o, dA1 + lo);
    async_copy16(gB0 + o, dB0 + lo);
    async_copy16(gB1 + o, dB1 + lo);
  };

  bf16x8 afX[4], afY[4], bfrP[4], bfrQ[4];

  // prologue: stage tiles 0,1; confirm slot 0 (slot 1's 4 loads stay in
  // flight); load tile-0 ph0 operands from slot 0.
  stage(0, 0);
  stage(1, 1);
  CKPT(4);
  RD_A(afX, 0, 0);
  RD_B(bfrP, 0);

  // main loop: K-tiles t = 0..27 (4 per iteration; bfr ping-pongs per tile,
  // af ping-pongs per phase, ring slot period 4)
  for (int t4 = 0; t4 < 7; ++t4) {
    const int tb = t4 * 4;
    TILE_BODY(0, 1, 2, tb + 2, bfrP, bfrQ, true, 4);
    TILE_BODY(1, 2, 3, tb + 3, bfrQ, bfrP, true, 4);
    TILE_BODY(2, 3, 0, tb + 4, bfrP, bfrQ, true, 4);
    TILE_BODY(3, 0, 1, tb + 5, bfrQ, bfrP, true, 4);
  }
  // tail: t = 28..31
  TILE_BODY(0, 1, 2, 30, bfrP, bfrQ, true, 4);
  TILE_BODY(1, 2, 3, 31, bfrQ, bfrP, true, 4);
  TILE_BODY(2, 3, 0, 0, bfrP, bfrQ, false, 0); // vmcnt(0): confirm slot 31
  // t = 31: both phases, no next-tile reads, no barrier needed after
  RD_A(afY, 3 * 8192, 1);
  MM_HALF(afX, bfrQ, 0);
  MM_HALF(afY, bfrQ, 1);

  // Swapped C/D mapping (R3-verified): m = lane&15 axis, n = (lane>>4)*4 + reg.
  const int mloc = lane & 15;
  const int nq = (lane >> 4) * 4;
#pragma unroll
  for (int i = 0; i < 8; ++i) {
    const long m = m0 + wm * 128 + i * 16 + mloc;
#pragma unroll
    for (int j = 0; j < 4; ++j) {
      const long nb = n0 + wn * 64 + j * 16 + nq; // 4 consecutive n
      const f32x4 v = acc[i][j];
      if (MODE == 0) {
        *(f32x4*)(outF + m * N + nb) = v;
      } else {
        float act[4];
        if (n0 < CC) { // sigmoid region (block-uniform; 256 | 1024)
#pragma unroll
          for (int r = 0; r < 4; ++r)
            act[r] = __builtin_amdgcn_rcpf(1.f + __expf(-v[r]));
        } else {       // tanh = 1 - 2/(exp(2v)+1)
#pragma unroll
          for (int r = 0; r < 4; ++r)
            act[r] = fmaf(-2.f, __builtin_amdgcn_rcpf(1.f + __expf(2.f * v[r])), 1.f);
        }
        ushort4 o;
        o.x = f2b(act[0]); o.y = f2b(act[1]); o.z = f2b(act[2]); o.w = f2b(act[3]);
        *(ushort4*)(outB + m * (long)N + nb) = o;
      }
    }
  }
}

// ===== Scan: R1-style 3-pass (cheapest measured), vectorized 4 chains/thread =====
// P layout: [m=b*T+t][0..1023]=f (bf16), [1024..2047]=g (bf16)
// R8: NCHUNK 64->128 (512 blocks for pass1/3 = 8 waves/CU, was 4).
__global__ __launch_bounds__(256) void scan_pass1(const ushort* __restrict__ P,
                                                  float* __restrict__ cA,
                                                  float* __restrict__ cB) {
  const int pc = blockIdx.x * 256 + threadIdx.x; // chain quad 0..1023
  const int chunk = blockIdx.y;
  const int b = pc >> 8, c4 = (pc & 255) * 4;
  const ushort4* p =
      (const ushort4*)(P + (size_t)(b * TT + chunk * CHUNK_T) * (2 * CC) + c4);
  float A[4] = {1.f, 1.f, 1.f, 1.f};
  float h[4] = {0.f, 0.f, 0.f, 0.f};
#pragma unroll 4
  for (int i = 0; i < CHUNK_T; ++i) {
    const ushort4 fu = p[0];
    const ushort4 gu = p[CC / 4];
    p += 2 * CC / 4;
    const float f[4] = {b2f(fu.x), b2f(fu.y), b2f(fu.z), b2f(fu.w)};
    const float g[4] = {b2f(gu.x), b2f(gu.y), b2f(gu.z), b2f(gu.w)};
#pragma unroll
    for (int r = 0; r < 4; ++r) {
      A[r] *= f[r];
      h[r] = fmaf(f[r], h[r], (1.f - f[r]) * g[r]);
    }
  }
  const int ci = chunk * NCHAIN + b * CC + c4;
  *(f32x4*)(cA + ci) = (f32x4){A[0], A[1], A[2], A[3]};
  *(f32x4*)(cB + ci) = (f32x4){h[0], h[1], h[2], h[3]};
}

__global__ __launch_bounds__(256) void scan_pass2(const float* __restrict__ cA,
                                                  const float* __restrict__ cB,
                                                  float* __restrict__ hinit) {
  const int chain = blockIdx.x * 256 + threadIdx.x; // 0..4095
  float h = 0.f;
  for (int j = 0; j < NCHUNK; ++j) {
    hinit[j * NCHAIN + chain] = h; // exclusive carry
    h = fmaf(cA[j * NCHAIN + chain], h, cB[j * NCHAIN + chain]);
  }
}

__global__ __launch_bounds__(256) void scan_pass3(const ushort* __restrict__ P,
                                                  const float* __restrict__ hinit,
                                                  ushort* __restrict__ H) {
  const int pc = blockIdx.x * 256 + threadIdx.x;
  const int chunk = blockIdx.y;
  const int b = pc >> 8, c4 = (pc & 255) * 4;
  f32x4 hv = *(const f32x4*)(hinit + chunk * NCHAIN + b * CC + c4);
  float h[4] = {hv[0], hv[1], hv[2], hv[3]};
  const ushort4* p =
      (const ushort4*)(P + (size_t)(b * TT + chunk * CHUNK_T) * (2 * CC) + c4);
  ushort4* hp = (ushort4*)(H + (size_t)(b * TT + chunk * CHUNK_T) * CC + c4);
#pragma unroll 4
  for (int i = 0; i < CHUNK_T; ++i) {
    const ushort4 fu = p[0];
    const ushort4 gu = p[CC / 4];
    p += 2 * CC / 4;
    const float f[4] = {b2f(fu.x), b2f(fu.y), b2f(fu.z), b2f(fu.w)};
    const float g[4] = {b2f(gu.x), b2f(gu.y), b2f(gu.z), b2f(gu.w)};
    ushort4 o;
#pragma unroll
    for (int r = 0; r < 4; ++r)
      h[r] = fmaf(f[r], h[r], (1.f - f[r]) * g[r]);
    o.x = f2b(h[0]); o.y = f2b(h[1]); o.z = f2b(h[2]); o.w = f2b(h[3]);
    *hp = o;
    hp += CC / 4;
  }
}

extern "C" void kernel_launch(void* const* d_in, const int* in_sizes, int n_in,
                              void* d_out, int out_size, void* d_ws, size_t ws_size,
                              hipStream_t stream) {
  const float* x  = (const float*)d_in[0];
  const float* Wf = (const float*)d_in[1];
  const float* Wg = (const float*)d_in[2];
  const float* Wp = (const float*)d_in[3];

  // workspace layout (bytes); H aliases xb (xb dead after gates GEMM).
  // R8: cA/cB overlay Wcat (dead after gates GEMM; pass1 runs after it in
  // stream order; next graph iteration's cvt_all rewrite is also stream-
  // ordered after pass2's reads). hinit (2 MiB) lives in the tail, which
  // previously held 3 MiB -> total ws footprint unchanged vs R7.
  char* ws = (char*)d_ws;
  ushort* xb   = (ushort*)(ws);                                  // 33554432 B
  ushort* Hb   = xb;                                             // alias
  ushort* Wcat = (ushort*)(ws + 33554432);                       //  4194304 B (Wf||Wg)
  ushort* Wpb  = (ushort*)(ws + 33554432 + 4194304);             //  2097152 B
  ushort* P    = (ushort*)(ws + 33554432 + 4194304 + 2097152);   // 67108864 B (f||g bf16)
  char* tail   = ws + 33554432 + 4194304 + 2097152 + 67108864;
  float* cA    = (float*)Wcat;                                   // 2 MiB overlay
  float* cB    = (float*)(((char*)Wcat) + 2097152);              // 2 MiB overlay
  float* hinit = (float*)(tail);                                 // 2 MiB (128*4096*4)
  (void)ws_size; (void)in_sizes; (void)n_in; (void)out_size;

  // 1) all fp32 -> bf16 conversions in one launch
  cvt_all<<<19456, 256, 0, stream>>>(x, Wf, Wg, Wp, xb, Wcat, Wpb);

  // 2) gates GEMM: [16384 x 2048] = xb @ Wcat^T, fused sigmoid/tanh -> P (bf16)
  // 256x256 tiles: (2048/256) x (16384/256) = 512 blocks, 512 threads
  gemm_bt<1><<<512, 512, 0, stream>>>(xb, Wcat, nullptr, P, 2 * CC);

  // 3) chunked scan: 3-pass (per-chunk compose, carry scan, fixup)
  dim3 gs(NCHAIN / 4 / 256, NCHUNK);
  scan_pass1<<<gs, 256, 0, stream>>>(P, cA, cB);
  scan_pass2<<<NCHAIN / 256, 256, 0, stream>>>(cA, cB, hinit);
  scan_pass3<<<gs, 256, 0, stream>>>(P, hinit, Hb);

  // 4) projection GEMM: out = H @ Wp^T (fp32), 256x256 tiles -> 256 blocks
  gemm_bt<0><<<256, 512, 0, stream>>>(Hb, Wpb, (float*)d_out, nullptr, CC);
}